// Round 5
// baseline (431.352 us; speedup 1.0000x reference)
//
#include <hip/hip_runtime.h>
#include <stdint.h>
#include <stddef.h>

typedef __bf16 bf16_t;
typedef __bf16 bf16x8 __attribute__((ext_vector_type(8)));
typedef float  f32x4  __attribute__((ext_vector_type(4)));

#define NIMG 16
#define CIN  128
#define COUT 128
#define HH   56
#define WW   56
#define HW   (HH * WW)       // 3136
#define CDIM 58              // staged c extent: c = w+1, w = -1..56
#define LSTR 136             // LDS c-stride in bf16: 272B = 68 dwords -> bank stride 4
#define ROWPAIRS 28
#define REPS 2               // DIAGNOSTIC: run conv body twice (idempotent) so the conv
                             // dispatch rises above the ~43us harness fills in the top-5
                             // profile and we finally get its counters. Set to 1 after
                             // the attribution round.

// ---------- prologue: W[co][ci][3][3] fp32 -> Wt2 fragment-major bf16 ----------
// one thread per 16B output run (rec,lane); 288 recs * 64 lanes = 18432 thr = 72 blocks
// rec = (khkw*4+chunk)*8 + cotile; element (lane=l4*16+l15, j) =
//   W[co=cotile*16+l15][ci=chunk*32+l4*8+j][khkw]
__global__ void wtrans_kernel(const float* __restrict__ w, bf16_t* __restrict__ wt2) {
    int t = blockIdx.x * 256 + threadIdx.x;       // exactly 18432 threads
    int lane = t & 63, rec = t >> 6;              // rec 0..287
    int l15 = lane & 15, l4 = lane >> 4;
    int cotile = rec & 7, chunk = (rec >> 3) & 3, khkw = rec >> 5;
    int co  = cotile * 16 + l15;
    int ci0 = chunk * 32 + l4 * 8;
    const float* src = w + ((size_t)co * CIN + ci0) * 9 + khkw;
    bf16x8 o;
#pragma unroll
    for (int j = 0; j < 8; ++j) o[j] = (bf16_t)src[(size_t)j * 9];
    *(bf16x8*)(wt2 + (size_t)rec * 512 + (size_t)lane * 8) = o;
}

// ---------- fused conv: block = (n, 2 rows) x 128 co; 512 thr = 8 waves ----------
// wave = ks*4 + wc*2 + ws: tile 64sp x 64co (tc=4, ts=4), K split in half by ks
// (chunks {2ks,2ks+1} x 9 khkw = 18 phases). LDS cross-wave reduce at the end.
#define FRAG_OFF(I) ((size_t)((((I) >> 1) * 4 + ((I) & 1)) * 8) * 512)

#define MFMA_COL(Mv, TS, F0v, F1v, F2v, F3v)                                          \
    acc[0][TS] = __builtin_amdgcn_mfma_f32_16x16x32_bf16(F0v, Mv, acc[0][TS], 0,0,0); \
    acc[1][TS] = __builtin_amdgcn_mfma_f32_16x16x32_bf16(F1v, Mv, acc[1][TS], 0,0,0); \
    acc[2][TS] = __builtin_amdgcn_mfma_f32_16x16x32_bf16(F2v, Mv, acc[2][TS], 0,0,0); \
    acc[3][TS] = __builtin_amdgcn_mfma_f32_16x16x32_bf16(F3v, Mv, acc[3][TS], 0,0,0);

// All LDS B addresses = per-lane base + compile-time byte immediate (max 40,864 B,
// fits the 16-bit ds offset). Only ts=3 can clamp (ts<=2 max col = 49 <= 57), so
// ts=3 uses one of 3 precomputed clamped bases (selected at compile time per kw).
#define DO_PHASE(I, F0v, F1v, F2v, F3v) do {                                          \
    const int kh_ = ((I) >> 1) / 3, kw_ = ((I) >> 1) % 3, cs_ = (I) & 1;              \
    const bf16_t* b0_ = pB + (size_t)(kh_ * CDIM + kw_) * LSTR + cs_ * 32;            \
    const bf16_t* pb3_ = (kw_ == 0) ? pB3_0 : ((kw_ == 1) ? pB3_1 : pB3_2);           \
    const bf16_t* b3_ = pb3_ + (size_t)(kh_ * CDIM) * LSTR + cs_ * 32;                \
    bf16x8 m0_ = *(const bf16x8*)(b0_);                                               \
    bf16x8 m1_ = *(const bf16x8*)(b0_ + 16 * LSTR);                                   \
    bf16x8 m2_ = *(const bf16x8*)(b0_ + 32 * LSTR);                                   \
    bf16x8 m3_ = *(const bf16x8*)(b3_);                                               \
    __builtin_amdgcn_s_setprio(1);                                                    \
    MFMA_COL(m0_, 0, F0v, F1v, F2v, F3v)                                              \
    MFMA_COL(m1_, 1, F0v, F1v, F2v, F3v)                                              \
    MFMA_COL(m2_, 2, F0v, F1v, F2v, F3v)                                              \
    MFMA_COL(m3_, 3, F0v, F1v, F2v, F3v)                                              \
    __builtin_amdgcn_s_setprio(0);                                                    \
} while (0)

#define PREFETCH(I, F0v, F1v, F2v, F3v) do {                                          \
    const bf16_t* wp_ = wpbase + FRAG_OFF(I);                                         \
    F0v = *(const bf16x8*)(wp_);                                                      \
    F1v = *(const bf16x8*)(wp_ + 512);                                                \
    F2v = *(const bf16x8*)(wp_ + 1024);                                               \
    F3v = *(const bf16x8*)(wp_ + 1536);                                               \
} while (0)

__global__ __launch_bounds__(512, 4)
void conv_fused_kernel(const float* __restrict__ in, const bf16_t* __restrict__ Wt2,
                       const float* __restrict__ bias, float* __restrict__ out) {
    __shared__ __align__(16) unsigned char smem[65536];   // input stage 63104 B / reduce 65536 B
    bf16_t* inp = (bf16_t*)smem;

    // XCD-aware swizzle: grid 448 = 8 XCDs x 56 blocks -> each XCD gets 2 whole
    // images (halo row re-reads become L2 hits).
    const int bx0 = blockIdx.x;
    const int bx  = (bx0 & 7) * 56 + (bx0 >> 3);

    const int n  = bx / ROWPAIRS;
    const int h0 = (bx % ROWPAIRS) * 2;          // output rows h0,h0+1; input rows h0-1..h0+2

    const int tid  = threadIdx.x;
    const int lane = tid & 63;
    const int wave = tid >> 6;                   // 0..7
    const int ws  = wave & 1;                    // output row within pair
    const int wc  = (wave >> 1) & 1;             // co half (64)
    const int ks  = wave >> 2;                   // K half (chunks 2ks, 2ks+1)
    const int l15 = lane & 15;
    const int l4  = lane >> 4;

    // LDS B bases (ws, ks, lane folded in; all phase offsets are compile-time imms)
    const bf16_t* pB = inp + (size_t)(ws * CDIM + l15) * LSTR + ks * 64 + l4 * 8;
    int c3_0 = 48 + l15;     if (c3_0 > 57) c3_0 = 57;    // ts=3 clamped cols per kw
    int c3_1 = 48 + l15 + 1; if (c3_1 > 57) c3_1 = 57;
    int c3_2 = 48 + l15 + 2; if (c3_2 > 57) c3_2 = 57;
    const bf16_t* pB3_0 = inp + (size_t)(ws * CDIM + c3_0) * LSTR + ks * 64 + l4 * 8;
    const bf16_t* pB3_1 = inp + (size_t)(ws * CDIM + c3_1) * LSTR + ks * 64 + l4 * 8;
    const bf16_t* pB3_2 = inp + (size_t)(ws * CDIM + c3_2) * LSTR + ks * 64 + l4 * 8;

    // weight fragment base: rec = (khkw*4 + ks*2 + cs)*8 + wc*4 + tc
    const bf16_t* wpbase = Wt2 + (size_t)(ks * 16 + wc * 4) * 512 + (size_t)lane * 8;

    for (int rep = 0; rep < REPS; ++rep) {
        // ---- stage input: unit G = cig*232 + rr*58 + c (c fastest -> contiguous walk)
#pragma unroll
        for (int it = 0; it < 7; ++it) {
            int G = it * 512 + tid;
            int cig = G / 232, rem = G - cig * 232;
            int rr  = rem / 58, c  = rem - rr * 58;
            int r_in = h0 - 1 + rr, w = c - 1;
            uint32_t u[8];
            if (r_in >= 0 && r_in < HH && w >= 0 && w < WW) {
                const float* src = in + (((size_t)n * CIN + cig * 8) * HH + r_in) * WW + w;
                float v[8];
#pragma unroll
                for (int j = 0; j < 8; ++j) v[j] = src[(size_t)j * HW];   // 8 independent loads
#pragma unroll
                for (int j = 0; j < 8; ++j) { bf16_t b = (bf16_t)v[j]; u[j] = *(const uint16_t*)&b; }
            } else {
#pragma unroll
                for (int j = 0; j < 8; ++j) u[j] = 0;
            }
            uint4 o;
            o.x = u[0] | (u[1] << 16); o.y = u[2] | (u[3] << 16);
            o.z = u[4] | (u[5] << 16); o.w = u[6] | (u[7] << 16);
            *(uint4*)&inp[(rr * CDIM + c) * LSTR + cig * 8] = o;
        }
        if (tid < 128) {
            int G = 3584 + tid;
            int cig = G / 232, rem = G - cig * 232;
            int rr  = rem / 58, c  = rem - rr * 58;
            int r_in = h0 - 1 + rr, w = c - 1;
            uint32_t u[8];
            if (r_in >= 0 && r_in < HH && w >= 0 && w < WW) {
                const float* src = in + (((size_t)n * CIN + cig * 8) * HH + r_in) * WW + w;
                float v[8];
#pragma unroll
                for (int j = 0; j < 8; ++j) v[j] = src[(size_t)j * HW];
#pragma unroll
                for (int j = 0; j < 8; ++j) { bf16_t b = (bf16_t)v[j]; u[j] = *(const uint16_t*)&b; }
            } else {
#pragma unroll
                for (int j = 0; j < 8; ++j) u[j] = 0;
            }
            uint4 o;
            o.x = u[0] | (u[1] << 16); o.y = u[2] | (u[3] << 16);
            o.z = u[4] | (u[5] << 16); o.w = u[6] | (u[7] << 16);
            *(uint4*)&inp[(rr * CDIM + c) * LSTR + cig * 8] = o;
        }
        __syncthreads();

        f32x4 acc[4][4];                             // [co tile][sp tile]
#pragma unroll
        for (int a = 0; a < 4; ++a)
#pragma unroll
            for (int b2 = 0; b2 < 4; ++b2) acc[a][b2] = (f32x4){0.f, 0.f, 0.f, 0.f};

        bf16x8 A0, A1, A2, A3, B0, B1, B2, B3;       // named regs, prefetch distance 2
        PREFETCH(0, A0, A1, A2, A3);
        PREFETCH(1, B0, B1, B2, B3);

#pragma unroll
        for (int ii = 0; ii < 8; ++ii) {
            const int i0 = ii * 2;
            DO_PHASE(i0, A0, A1, A2, A3);
            PREFETCH(i0 + 2, A0, A1, A2, A3);
            DO_PHASE(i0 + 1, B0, B1, B2, B3);
            PREFETCH(i0 + 3, B0, B1, B2, B3);
        }
        DO_PHASE(16, A0, A1, A2, A3);
        DO_PHASE(17, B0, B1, B2, B3);

        // ---- cross-wave K reduction through LDS (pair (ws,wc,ks=1) -> (ws,wc,ks=0))
        __syncthreads();                             // K-loop LDS reads done; safe to overwrite
        float* red = (float*)smem;
        const int q = wc * 2 + ws;                   // 0..3
        if (ks == 1) {
#pragma unroll
            for (int tc = 0; tc < 4; ++tc)
#pragma unroll
                for (int ts = 0; ts < 4; ++ts)
                    *(f32x4*)(red + (size_t)q * 4096 + (tc * 4 + ts) * 256 + lane * 4) = acc[tc][ts];
        }
        __syncthreads();
        if (ks == 0) {
            const int h   = h0 + ws;
            const int co0 = wc * 64;
            float* obase = out + ((size_t)n * COUT) * HW + (size_t)h * WW;
#pragma unroll
            for (int tc = 0; tc < 4; ++tc) {
#pragma unroll
                for (int ts = 0; ts < 4; ++ts) {
                    f32x4 oth = *(const f32x4*)(red + (size_t)q * 4096 + (tc * 4 + ts) * 256 + lane * 4);
                    f32x4 r = acc[tc][ts] + oth;
                    int w0 = ts * 16 + l15;
                    if (w0 < WW) {
#pragma unroll
                        for (int i = 0; i < 4; ++i) {
                            int co = co0 + tc * 16 + l4 * 4 + i;
                            obase[(size_t)co * HW + w0] = r[i] + bias[co];
                        }
                    }
                }
            }
        }
        __syncthreads();                             // rep boundary: red reads done before restage
    }
}

extern "C" void kernel_launch(void* const* d_in, const int* in_sizes, int n_in,
                              void* d_out, int out_size, void* d_ws, size_t ws_size,
                              hipStream_t stream) {
    const float* in   = (const float*)d_in[0];
    const float* wgt  = (const float*)d_in[1];
    const float* bias = (const float*)d_in[2];
    float* out = (float*)d_out;

    bf16_t* Wt2 = (bf16_t*)d_ws;                 // 294,912 B, fragment-major

    wtrans_kernel<<<72, 256, 0, stream>>>(wgt, Wt2);
    conv_fused_kernel<<<NIMG * ROWPAIRS, 512, 0, stream>>>(in, Wt2, bias, out);
}

// Round 6
// 188.381 us; speedup vs baseline: 2.2898x; 2.2898x over previous
//
#include <hip/hip_runtime.h>
#include <stdint.h>
#include <stddef.h>

typedef __bf16 bf16_t;
typedef __bf16 bf16x8 __attribute__((ext_vector_type(8)));
typedef float  f32x4  __attribute__((ext_vector_type(4)));

#define NIMG 16
#define CIN  128
#define COUT 128
#define HH   56
#define WW   56
#define HW   (HH * WW)       // 3136
#define CDIM 58              // staged c extent: c = w+1, w = -1..56
#define LSTR 136             // LDS c-stride in bf16: 272B = 68 dwords -> bank stride 4
#define ROWPAIRS 28
// DIAGNOSTIC round: body invoked TWICE (idempotent) so the conv dispatch rises above
// the ~43us harness fills and yields counters. R5's rep-LOOP made the compiler chase
// 8 waves/EU (VGPR 64 + ~700MB scratch spill, 370us). This version: (a) occupancy
// pinned to 4 waves/EU so the allocator gets the full 128-VGPR budget, (b) two
// explicit inlined body calls, no loop backedge -> each body compiles like REPS=1.

// ---------- prologue: W[co][ci][3][3] fp32 -> Wt2 fragment-major bf16 ----------
// one thread per 16B output run (rec,lane); 288 recs * 64 lanes = 18432 thr = 72 blocks
// rec = (khkw*4+chunk)*8 + cotile; element (lane=l4*16+l15, j) =
//   W[co=cotile*16+l15][ci=chunk*32+l4*8+j][khkw]
__global__ void wtrans_kernel(const float* __restrict__ w, bf16_t* __restrict__ wt2) {
    int t = blockIdx.x * 256 + threadIdx.x;       // exactly 18432 threads
    int lane = t & 63, rec = t >> 6;              // rec 0..287
    int l15 = lane & 15, l4 = lane >> 4;
    int cotile = rec & 7, chunk = (rec >> 3) & 3, khkw = rec >> 5;
    int co  = cotile * 16 + l15;
    int ci0 = chunk * 32 + l4 * 8;
    const float* src = w + ((size_t)co * CIN + ci0) * 9 + khkw;
    bf16x8 o;
#pragma unroll
    for (int j = 0; j < 8; ++j) o[j] = (bf16_t)src[(size_t)j * 9];
    *(bf16x8*)(wt2 + (size_t)rec * 512 + (size_t)lane * 8) = o;
}

// ---------- fused conv: block = (n, 2 rows) x 128 co; 512 thr = 8 waves ----------
// wave = ks*4 + wc*2 + ws: tile 64sp x 64co (tc=4, ts=4), K split in half by ks
// (chunks {2ks,2ks+1} x 9 khkw = 18 phases). LDS cross-wave reduce at the end.
#define FRAG_OFF(I) ((size_t)((((I) >> 1) * 4 + ((I) & 1)) * 8) * 512)

#define MFMA_COL(Mv, TS, F0v, F1v, F2v, F3v)                                          \
    acc[0][TS] = __builtin_amdgcn_mfma_f32_16x16x32_bf16(F0v, Mv, acc[0][TS], 0,0,0); \
    acc[1][TS] = __builtin_amdgcn_mfma_f32_16x16x32_bf16(F1v, Mv, acc[1][TS], 0,0,0); \
    acc[2][TS] = __builtin_amdgcn_mfma_f32_16x16x32_bf16(F2v, Mv, acc[2][TS], 0,0,0); \
    acc[3][TS] = __builtin_amdgcn_mfma_f32_16x16x32_bf16(F3v, Mv, acc[3][TS], 0,0,0);

// All LDS B addresses = per-lane base + compile-time byte immediate (max 40,864 B,
// fits the 16-bit ds offset). Only ts=3 can clamp (ts<=2 max col = 49 <= 57), so
// ts=3 uses one of 3 precomputed clamped bases (selected at compile time per kw).
#define DO_PHASE(I, F0v, F1v, F2v, F3v) do {                                          \
    const int kh_ = ((I) >> 1) / 3, kw_ = ((I) >> 1) % 3, cs_ = (I) & 1;              \
    const bf16_t* b0_ = pB + (size_t)(kh_ * CDIM + kw_) * LSTR + cs_ * 32;            \
    const bf16_t* pb3_ = (kw_ == 0) ? pB3_0 : ((kw_ == 1) ? pB3_1 : pB3_2);           \
    const bf16_t* b3_ = pb3_ + (size_t)(kh_ * CDIM) * LSTR + cs_ * 32;                \
    bf16x8 m0_ = *(const bf16x8*)(b0_);                                               \
    bf16x8 m1_ = *(const bf16x8*)(b0_ + 16 * LSTR);                                   \
    bf16x8 m2_ = *(const bf16x8*)(b0_ + 32 * LSTR);                                   \
    bf16x8 m3_ = *(const bf16x8*)(b3_);                                               \
    __builtin_amdgcn_s_setprio(1);                                                    \
    MFMA_COL(m0_, 0, F0v, F1v, F2v, F3v)                                              \
    MFMA_COL(m1_, 1, F0v, F1v, F2v, F3v)                                              \
    MFMA_COL(m2_, 2, F0v, F1v, F2v, F3v)                                              \
    MFMA_COL(m3_, 3, F0v, F1v, F2v, F3v)                                              \
    __builtin_amdgcn_s_setprio(0);                                                    \
} while (0)

#define PREFETCH(I, F0v, F1v, F2v, F3v) do {                                          \
    const bf16_t* wp_ = wpbase + FRAG_OFF(I);                                         \
    F0v = *(const bf16x8*)(wp_);                                                      \
    F1v = *(const bf16x8*)(wp_ + 512);                                                \
    F2v = *(const bf16x8*)(wp_ + 1024);                                               \
    F3v = *(const bf16x8*)(wp_ + 1536);                                               \
} while (0)

__global__ __launch_bounds__(512) __attribute__((amdgpu_waves_per_eu(4, 4)))
void conv_fused_kernel(const float* __restrict__ in, const bf16_t* __restrict__ Wt2,
                       const float* __restrict__ bias, float* __restrict__ out) {
    __shared__ __align__(16) unsigned char smem[65536];   // input stage 63104 B / reduce 65536 B
    bf16_t* inp = (bf16_t*)smem;

    // XCD-aware swizzle: grid 448 = 8 XCDs x 56 blocks -> each XCD gets 2 whole
    // images (halo row re-reads become L2 hits).
    const int bx0 = blockIdx.x;
    const int bx  = (bx0 & 7) * 56 + (bx0 >> 3);

    const int n  = bx / ROWPAIRS;
    const int h0 = (bx % ROWPAIRS) * 2;          // output rows h0,h0+1; input rows h0-1..h0+2

    const int tid  = threadIdx.x;
    const int lane = tid & 63;
    const int wave = tid >> 6;                   // 0..7
    const int ws  = wave & 1;                    // output row within pair
    const int wc  = (wave >> 1) & 1;             // co half (64)
    const int ks  = wave >> 2;                   // K half (chunks 2ks, 2ks+1)
    const int l15 = lane & 15;
    const int l4  = lane >> 4;

    // LDS B bases (ws, ks, lane folded in; all phase offsets are compile-time imms)
    const bf16_t* pB = inp + (size_t)(ws * CDIM + l15) * LSTR + ks * 64 + l4 * 8;
    int c3_0 = 48 + l15;     if (c3_0 > 57) c3_0 = 57;    // ts=3 clamped cols per kw
    int c3_1 = 48 + l15 + 1; if (c3_1 > 57) c3_1 = 57;
    int c3_2 = 48 + l15 + 2; if (c3_2 > 57) c3_2 = 57;
    const bf16_t* pB3_0 = inp + (size_t)(ws * CDIM + c3_0) * LSTR + ks * 64 + l4 * 8;
    const bf16_t* pB3_1 = inp + (size_t)(ws * CDIM + c3_1) * LSTR + ks * 64 + l4 * 8;
    const bf16_t* pB3_2 = inp + (size_t)(ws * CDIM + c3_2) * LSTR + ks * 64 + l4 * 8;

    // weight fragment base: rec = (khkw*4 + ks*2 + cs)*8 + wc*4 + tc
    const bf16_t* wpbase = Wt2 + (size_t)(ks * 16 + wc * 4) * 512 + (size_t)lane * 8;

    auto body = [&]() {
        // ---- stage input: unit G = cig*232 + rr*58 + c (c fastest -> contiguous walk)
#pragma unroll
        for (int it = 0; it < 7; ++it) {
            int G = it * 512 + tid;
            int cig = G / 232, rem = G - cig * 232;
            int rr  = rem / 58, c  = rem - rr * 58;
            int r_in = h0 - 1 + rr, w = c - 1;
            uint32_t u[8];
            if (r_in >= 0 && r_in < HH && w >= 0 && w < WW) {
                const float* src = in + (((size_t)n * CIN + cig * 8) * HH + r_in) * WW + w;
                float v[8];
#pragma unroll
                for (int j = 0; j < 8; ++j) v[j] = src[(size_t)j * HW];   // 8 independent loads
#pragma unroll
                for (int j = 0; j < 8; ++j) { bf16_t b = (bf16_t)v[j]; u[j] = *(const uint16_t*)&b; }
            } else {
#pragma unroll
                for (int j = 0; j < 8; ++j) u[j] = 0;
            }
            uint4 o;
            o.x = u[0] | (u[1] << 16); o.y = u[2] | (u[3] << 16);
            o.z = u[4] | (u[5] << 16); o.w = u[6] | (u[7] << 16);
            *(uint4*)&inp[(rr * CDIM + c) * LSTR + cig * 8] = o;
        }
        if (tid < 128) {
            int G = 3584 + tid;
            int cig = G / 232, rem = G - cig * 232;
            int rr  = rem / 58, c  = rem - rr * 58;
            int r_in = h0 - 1 + rr, w = c - 1;
            uint32_t u[8];
            if (r_in >= 0 && r_in < HH && w >= 0 && w < WW) {
                const float* src = in + (((size_t)n * CIN + cig * 8) * HH + r_in) * WW + w;
                float v[8];
#pragma unroll
                for (int j = 0; j < 8; ++j) v[j] = src[(size_t)j * HW];
#pragma unroll
                for (int j = 0; j < 8; ++j) { bf16_t b = (bf16_t)v[j]; u[j] = *(const uint16_t*)&b; }
            } else {
#pragma unroll
                for (int j = 0; j < 8; ++j) u[j] = 0;
            }
            uint4 o;
            o.x = u[0] | (u[1] << 16); o.y = u[2] | (u[3] << 16);
            o.z = u[4] | (u[5] << 16); o.w = u[6] | (u[7] << 16);
            *(uint4*)&inp[(rr * CDIM + c) * LSTR + cig * 8] = o;
        }
        __syncthreads();

        f32x4 acc[4][4];                             // [co tile][sp tile]
#pragma unroll
        for (int a = 0; a < 4; ++a)
#pragma unroll
            for (int b2 = 0; b2 < 4; ++b2) acc[a][b2] = (f32x4){0.f, 0.f, 0.f, 0.f};

        bf16x8 A0, A1, A2, A3, B0, B1, B2, B3;       // named regs, prefetch distance 2
        PREFETCH(0, A0, A1, A2, A3);
        PREFETCH(1, B0, B1, B2, B3);

#pragma unroll
        for (int ii = 0; ii < 8; ++ii) {
            const int i0 = ii * 2;
            DO_PHASE(i0, A0, A1, A2, A3);
            PREFETCH(i0 + 2, A0, A1, A2, A3);
            DO_PHASE(i0 + 1, B0, B1, B2, B3);
            PREFETCH(i0 + 3, B0, B1, B2, B3);
        }
        DO_PHASE(16, A0, A1, A2, A3);
        DO_PHASE(17, B0, B1, B2, B3);

        // ---- cross-wave K reduction through LDS (pair (ws,wc,ks=1) -> (ws,wc,ks=0))
        __syncthreads();                             // K-loop LDS reads done; safe to overwrite
        float* red = (float*)smem;
        const int q = wc * 2 + ws;                   // 0..3
        if (ks == 1) {
#pragma unroll
            for (int tc = 0; tc < 4; ++tc)
#pragma unroll
                for (int ts = 0; ts < 4; ++ts)
                    *(f32x4*)(red + (size_t)q * 4096 + (tc * 4 + ts) * 256 + lane * 4) = acc[tc][ts];
        }
        __syncthreads();
        if (ks == 0) {
            const int h   = h0 + ws;
            const int co0 = wc * 64;
            float* obase = out + ((size_t)n * COUT) * HW + (size_t)h * WW;
#pragma unroll
            for (int tc = 0; tc < 4; ++tc) {
#pragma unroll
                for (int ts = 0; ts < 4; ++ts) {
                    f32x4 oth = *(const f32x4*)(red + (size_t)q * 4096 + (tc * 4 + ts) * 256 + lane * 4);
                    f32x4 r = acc[tc][ts] + oth;
                    int w0 = ts * 16 + l15;
                    if (w0 < WW) {
#pragma unroll
                        for (int i = 0; i < 4; ++i) {
                            int co = co0 + tc * 16 + l4 * 4 + i;
                            obase[(size_t)co * HW + w0] = r[i] + bias[co];
                        }
                    }
                }
            }
        }
    };

    body();
    __syncthreads();   // rep boundary: red reads done before restage
    body();            // second, idempotent pass (diagnostic visibility only)
}

extern "C" void kernel_launch(void* const* d_in, const int* in_sizes, int n_in,
                              void* d_out, int out_size, void* d_ws, size_t ws_size,
                              hipStream_t stream) {
    const float* in   = (const float*)d_in[0];
    const float* wgt  = (const float*)d_in[1];
    const float* bias = (const float*)d_in[2];
    float* out = (float*)d_out;

    bf16_t* Wt2 = (bf16_t*)d_ws;                 // 294,912 B, fragment-major

    wtrans_kernel<<<72, 256, 0, stream>>>(wgt, Wt2);
    conv_fused_kernel<<<NIMG * ROWPAIRS, 512, 0, stream>>>(in, Wt2, bias, out);
}

// Round 7
// 96.499 us; speedup vs baseline: 4.4700x; 1.9522x over previous
//
#include <hip/hip_runtime.h>
#include <stdint.h>
#include <stddef.h>

typedef __bf16 bf16_t;
typedef __bf16 bf16x8 __attribute__((ext_vector_type(8)));
typedef float  f32x4  __attribute__((ext_vector_type(4)));

#define NIMG 16
#define CIN  128
#define COUT 128
#define HH   56
#define WW   56
#define HW   (HH * WW)       // 3136
#define CDIM 58              // staged c extent: c = w+1, w = -1..56
#define LSTR 136             // LDS c-stride in bf16: 272B = 68 dwords -> bank stride 4
#define ROWPAIRS 28

// R6 post-mortem: conv was SPILL-bound (VGPR_Count 64 + 64 AGPR acc = 128-reg unified
// budget; ~75 dwords/thread of K-loop arch state spilled -> ~70MB/launch scratch
// traffic, MfmaUtil 12%). This round: K-loop arch demand cut to ~55 regs (<=64) by
// loading LDS m-subtiles TWO at a time in their own scopes. acc stays in AGPRs.

// ---------- prologue: W[co][ci][3][3] fp32 -> Wt2 fragment-major bf16 ----------
// one thread per 16B output run (rec,lane); 288 recs * 64 lanes = 18432 thr = 72 blocks
// rec = (khkw*4+chunk)*8 + cotile; element (lane=l4*16+l15, j) =
//   W[co=cotile*16+l15][ci=chunk*32+l4*8+j][khkw]
__global__ void wtrans_kernel(const float* __restrict__ w, bf16_t* __restrict__ wt2) {
    int t = blockIdx.x * 256 + threadIdx.x;       // exactly 18432 threads
    int lane = t & 63, rec = t >> 6;              // rec 0..287
    int l15 = lane & 15, l4 = lane >> 4;
    int cotile = rec & 7, chunk = (rec >> 3) & 3, khkw = rec >> 5;
    int co  = cotile * 16 + l15;
    int ci0 = chunk * 32 + l4 * 8;
    const float* src = w + ((size_t)co * CIN + ci0) * 9 + khkw;
    bf16x8 o;
#pragma unroll
    for (int j = 0; j < 8; ++j) o[j] = (bf16_t)src[(size_t)j * 9];
    *(bf16x8*)(wt2 + (size_t)rec * 512 + (size_t)lane * 8) = o;
}

// ---------- fused conv: block = (n, 2 rows) x 128 co; 512 thr = 8 waves ----------
// wave = ks*4 + wc*2 + ws: tile 64sp x 64co (tc=4, ts=4), K split in half by ks
// (chunks {2ks,2ks+1} x 9 khkw = 18 phases). LDS cross-wave reduce at the end.
#define FRAG_OFF(I) ((size_t)((((I) >> 1) * 4 + ((I) & 1)) * 8) * 512)

#define MFMA_COL(Mv, TS, F0v, F1v, F2v, F3v)                                          \
    acc[0][TS] = __builtin_amdgcn_mfma_f32_16x16x32_bf16(F0v, Mv, acc[0][TS], 0,0,0); \
    acc[1][TS] = __builtin_amdgcn_mfma_f32_16x16x32_bf16(F1v, Mv, acc[1][TS], 0,0,0); \
    acc[2][TS] = __builtin_amdgcn_mfma_f32_16x16x32_bf16(F2v, Mv, acc[2][TS], 0,0,0); \
    acc[3][TS] = __builtin_amdgcn_mfma_f32_16x16x32_bf16(F3v, Mv, acc[3][TS], 0,0,0);

// All LDS B addresses = per-lane base + compile-time byte immediate (max 40,864 B,
// fits the 16-bit ds offset). Only ts=3 can clamp (ts<=2 max col = 49 <= 57), so
// ts=3 uses one of 3 precomputed clamped bases (selected at compile time per kw).
// m-subtiles loaded TWO at a time in their own scopes: 8 live arch regs, not 16.
#define DO_PHASE(I, F0v, F1v, F2v, F3v) do {                                          \
    const int kh_ = ((I) >> 1) / 3, kw_ = ((I) >> 1) % 3, cs_ = (I) & 1;              \
    const bf16_t* b0_ = pB + (size_t)(kh_ * CDIM + kw_) * LSTR + cs_ * 32;            \
    {                                                                                 \
        bf16x8 m0_ = *(const bf16x8*)(b0_);                                           \
        bf16x8 m1_ = *(const bf16x8*)(b0_ + 16 * LSTR);                               \
        __builtin_amdgcn_s_setprio(1);                                                \
        MFMA_COL(m0_, 0, F0v, F1v, F2v, F3v)                                          \
        MFMA_COL(m1_, 1, F0v, F1v, F2v, F3v)                                          \
        __builtin_amdgcn_s_setprio(0);                                                \
    }                                                                                 \
    {                                                                                 \
        const bf16_t* pb3_ = (kw_ == 0) ? pB3_0 : ((kw_ == 1) ? pB3_1 : pB3_2);       \
        const bf16_t* b3_ = pb3_ + (size_t)(kh_ * CDIM) * LSTR + cs_ * 32;            \
        bf16x8 m2_ = *(const bf16x8*)(b0_ + 32 * LSTR);                               \
        bf16x8 m3_ = *(const bf16x8*)(b3_);                                           \
        __builtin_amdgcn_s_setprio(1);                                                \
        MFMA_COL(m2_, 2, F0v, F1v, F2v, F3v)                                          \
        MFMA_COL(m3_, 3, F0v, F1v, F2v, F3v)                                          \
        __builtin_amdgcn_s_setprio(0);                                                \
    }                                                                                 \
} while (0)

#define PREFETCH(I, F0v, F1v, F2v, F3v) do {                                          \
    const bf16_t* wp_ = wpbase + FRAG_OFF(I);                                         \
    F0v = *(const bf16x8*)(wp_);                                                      \
    F1v = *(const bf16x8*)(wp_ + 512);                                                \
    F2v = *(const bf16x8*)(wp_ + 1024);                                               \
    F3v = *(const bf16x8*)(wp_ + 1536);                                               \
} while (0)

__global__ __launch_bounds__(512) __attribute__((amdgpu_waves_per_eu(4, 4)))
void conv_fused_kernel(const float* __restrict__ in, const bf16_t* __restrict__ Wt2,
                       const float* __restrict__ bias, float* __restrict__ out) {
    __shared__ __align__(16) unsigned char smem[65536];   // input stage 63104 B / reduce 65536 B
    bf16_t* inp = (bf16_t*)smem;

    // XCD-aware swizzle: grid 448 = 8 XCDs x 56 blocks -> each XCD gets 2 whole
    // images (halo row re-reads become L2 hits).
    const int bx0 = blockIdx.x;
    const int bx  = (bx0 & 7) * 56 + (bx0 >> 3);

    const int n  = bx / ROWPAIRS;
    const int h0 = (bx % ROWPAIRS) * 2;          // output rows h0,h0+1; input rows h0-1..h0+2

    const int tid  = threadIdx.x;
    const int lane = tid & 63;
    const int wave = tid >> 6;                   // 0..7
    const int ws  = wave & 1;                    // output row within pair
    const int wc  = (wave >> 1) & 1;             // co half (64)
    const int ks  = wave >> 2;                   // K half (chunks 2ks, 2ks+1)
    const int l15 = lane & 15;
    const int l4  = lane >> 4;

    // ---- stage input: unit G = cig*232 + rr*58 + c (c fastest -> contiguous walk)
#pragma unroll
    for (int it = 0; it < 7; ++it) {
        int G = it * 512 + tid;
        int cig = G / 232, rem = G - cig * 232;
        int rr  = rem / 58, c  = rem - rr * 58;
        int r_in = h0 - 1 + rr, w = c - 1;
        uint32_t u[8];
        if (r_in >= 0 && r_in < HH && w >= 0 && w < WW) {
            const float* src = in + (((size_t)n * CIN + cig * 8) * HH + r_in) * WW + w;
            float v[8];
#pragma unroll
            for (int j = 0; j < 8; ++j) v[j] = src[(size_t)j * HW];   // 8 independent loads
#pragma unroll
            for (int j = 0; j < 8; ++j) { bf16_t b = (bf16_t)v[j]; u[j] = *(const uint16_t*)&b; }
        } else {
#pragma unroll
            for (int j = 0; j < 8; ++j) u[j] = 0;
        }
        uint4 o;
        o.x = u[0] | (u[1] << 16); o.y = u[2] | (u[3] << 16);
        o.z = u[4] | (u[5] << 16); o.w = u[6] | (u[7] << 16);
        *(uint4*)&inp[(rr * CDIM + c) * LSTR + cig * 8] = o;
    }
    if (tid < 128) {
        int G = 3584 + tid;
        int cig = G / 232, rem = G - cig * 232;
        int rr  = rem / 58, c  = rem - rr * 58;
        int r_in = h0 - 1 + rr, w = c - 1;
        uint32_t u[8];
        if (r_in >= 0 && r_in < HH && w >= 0 && w < WW) {
            const float* src = in + (((size_t)n * CIN + cig * 8) * HH + r_in) * WW + w;
            float v[8];
#pragma unroll
            for (int j = 0; j < 8; ++j) v[j] = src[(size_t)j * HW];
#pragma unroll
            for (int j = 0; j < 8; ++j) { bf16_t b = (bf16_t)v[j]; u[j] = *(const uint16_t*)&b; }
        } else {
#pragma unroll
            for (int j = 0; j < 8; ++j) u[j] = 0;
        }
        uint4 o;
        o.x = u[0] | (u[1] << 16); o.y = u[2] | (u[3] << 16);
        o.z = u[4] | (u[5] << 16); o.w = u[6] | (u[7] << 16);
        *(uint4*)&inp[(rr * CDIM + c) * LSTR + cig * 8] = o;
    }
    __syncthreads();

    f32x4 acc[4][4];                             // [co tile][sp tile] -> AGPRs (64)
#pragma unroll
    for (int a = 0; a < 4; ++a)
#pragma unroll
        for (int b2 = 0; b2 < 4; ++b2) acc[a][b2] = (f32x4){0.f, 0.f, 0.f, 0.f};

    // LDS B bases (ws, ks, lane folded in; all phase offsets are compile-time imms)
    const bf16_t* pB = inp + (size_t)(ws * CDIM + l15) * LSTR + ks * 64 + l4 * 8;
    int c3_0 = 48 + l15;     if (c3_0 > 57) c3_0 = 57;    // ts=3 clamped cols per kw
    int c3_1 = 48 + l15 + 1; if (c3_1 > 57) c3_1 = 57;
    int c3_2 = 48 + l15 + 2; if (c3_2 > 57) c3_2 = 57;
    const bf16_t* pB3_0 = inp + (size_t)(ws * CDIM + c3_0) * LSTR + ks * 64 + l4 * 8;
    const bf16_t* pB3_1 = inp + (size_t)(ws * CDIM + c3_1) * LSTR + ks * 64 + l4 * 8;
    const bf16_t* pB3_2 = inp + (size_t)(ws * CDIM + c3_2) * LSTR + ks * 64 + l4 * 8;

    // weight fragment base: rec = (khkw*4 + ks*2 + cs)*8 + wc*4 + tc
    const bf16_t* wpbase = Wt2 + (size_t)(ks * 16 + wc * 4) * 512 + (size_t)lane * 8;

    bf16x8 A0, A1, A2, A3, B0, B1, B2, B3;       // named regs, prefetch distance 2
    PREFETCH(0, A0, A1, A2, A3);
    PREFETCH(1, B0, B1, B2, B3);

#pragma unroll
    for (int ii = 0; ii < 8; ++ii) {
        const int i0 = ii * 2;
        DO_PHASE(i0, A0, A1, A2, A3);
        PREFETCH(i0 + 2, A0, A1, A2, A3);
        DO_PHASE(i0 + 1, B0, B1, B2, B3);
        PREFETCH(i0 + 3, B0, B1, B2, B3);
    }
    DO_PHASE(16, A0, A1, A2, A3);
    DO_PHASE(17, B0, B1, B2, B3);

    // ---- cross-wave K reduction through LDS (pair (ws,wc,ks=1) -> (ws,wc,ks=0))
    __syncthreads();                             // K-loop LDS reads done; safe to overwrite
    float* red = (float*)smem;
    const int q = wc * 2 + ws;                   // 0..3
    if (ks == 1) {
#pragma unroll
        for (int tc = 0; tc < 4; ++tc)
#pragma unroll
            for (int ts = 0; ts < 4; ++ts)
                *(f32x4*)(red + (size_t)q * 4096 + (tc * 4 + ts) * 256 + lane * 4) = acc[tc][ts];
    }
    __syncthreads();
    if (ks == 0) {
        const int h   = h0 + ws;
        const int co0 = wc * 64;
        float* obase = out + ((size_t)n * COUT) * HW + (size_t)h * WW;
#pragma unroll
        for (int tc = 0; tc < 4; ++tc) {
#pragma unroll
            for (int ts = 0; ts < 4; ++ts) {
                f32x4 oth = *(const f32x4*)(red + (size_t)q * 4096 + (tc * 4 + ts) * 256 + lane * 4);
                f32x4 r = acc[tc][ts] + oth;
                int w0 = ts * 16 + l15;
                if (w0 < WW) {
#pragma unroll
                    for (int i = 0; i < 4; ++i) {
                        int co = co0 + tc * 16 + l4 * 4 + i;
                        obase[(size_t)co * HW + w0] = r[i] + bias[co];
                    }
                }
            }
        }
    }
}

extern "C" void kernel_launch(void* const* d_in, const int* in_sizes, int n_in,
                              void* d_out, int out_size, void* d_ws, size_t ws_size,
                              hipStream_t stream) {
    const float* in   = (const float*)d_in[0];
    const float* wgt  = (const float*)d_in[1];
    const float* bias = (const float*)d_in[2];
    float* out = (float*)d_out;

    bf16_t* Wt2 = (bf16_t*)d_ws;                 // 294,912 B, fragment-major

    wtrans_kernel<<<72, 256, 0, stream>>>(wgt, Wt2);
    conv_fused_kernel<<<NIMG * ROWPAIRS, 512, 0, stream>>>(in, Wt2, bias, out);
}

// Round 8
// 95.412 us; speedup vs baseline: 4.5209x; 1.0114x over previous
//
#include <hip/hip_runtime.h>
#include <stdint.h>
#include <stddef.h>

typedef __bf16 bf16_t;
typedef __bf16 bf16x8 __attribute__((ext_vector_type(8)));
typedef float  f32x4  __attribute__((ext_vector_type(4)));

#define NIMG 16
#define CIN  128
#define COUT 128
#define HH   56
#define WW   56
#define HW   (HH * WW)       // 3136
#define CDIM 58              // staged c extent: c = w+1, w = -1..56
#define LSTR 136             // LDS c-stride in bf16: 272B = 68 dwords -> bank stride 4
#define ROWPAIRS 28

// R8 restructure: waves = ws(2) x wc(4), full K per wave (no ks split).
//  - acc[2][4] = 32 AGPR (was 64), frags 16 VGPR (was 32): kills the R6 spill regime
//    (unified-file budget 128/thread at 4 waves/EU; live state now ~80).
//  - no cross-wave K-reduce epilogue: each wave stores its 2x(32co)x64sp outputs.
//  - split staging: ci 0..63 -> barrier -> phases 0..17 (read record bytes 0..127)
//    overlapped with ci 64..127 staging (writes bytes 128..255, disjoint);
//    one barrier before phase 18.

// ---------- prologue: W[co][ci][3][3] fp32 -> Wt2 fragment-major bf16 ----------
// one thread per 16B output run (rec,lane); 288 recs * 64 lanes = 18432 thr = 72 blocks
// rec = (khkw*4+chunk)*8 + cotile; element (lane=l4*16+l15, j) =
//   W[co=cotile*16+l15][ci=chunk*32+l4*8+j][khkw]
__global__ void wtrans_kernel(const float* __restrict__ w, bf16_t* __restrict__ wt2) {
    int t = blockIdx.x * 256 + threadIdx.x;       // exactly 18432 threads
    int lane = t & 63, rec = t >> 6;              // rec 0..287
    int l15 = lane & 15, l4 = lane >> 4;
    int cotile = rec & 7, chunk = (rec >> 3) & 3, khkw = rec >> 5;
    int co  = cotile * 16 + l15;
    int ci0 = chunk * 32 + l4 * 8;
    const float* src = w + ((size_t)co * CIN + ci0) * 9 + khkw;
    bf16x8 o;
#pragma unroll
    for (int j = 0; j < 8; ++j) o[j] = (bf16_t)src[(size_t)j * 9];
    *(bf16x8*)(wt2 + (size_t)rec * 512 + (size_t)lane * 8) = o;
}

// ---------- fused conv: block = (n, 2 rows) x 128 co; 512 thr = 8 waves ----------
// wave = wc*2 + ws: ws = output row within pair, wc = cout quarter (32).
// 36 phases: I in [0,36), half = I/18, j = I%18, khkw = j>>1, cs = j&1,
// chunk = half*2 + cs, kh = khkw/3, kw = khkw%3. 8 MFMA/phase (tc 0..1 x ts 0..3).
#define FRAG_OFF(I) ((size_t)((((((I) % 18) >> 1) * 4 + (((I) / 18) * 2 + ((I) & 1))) * 8)) * 512)

// All LDS B addresses = per-lane base + compile-time byte immediate (max ~41 KB,
// fits the 16-bit ds offset). Only ts=3 can clamp (ts<=2 max col = 49 <= 57), so
// ts=3 uses one of 3 precomputed clamped bases (selected at compile time per kw).
#define DO_PHASE(I, F0v, F1v) do {                                                    \
    const int kh_ = (((I) % 18) >> 1) / 3, kw_ = (((I) % 18) >> 1) % 3;               \
    const int cio_ = ((I) / 18) * 64 + ((I) & 1) * 32;                                \
    const bf16_t* b0_ = pB + (size_t)(kh_ * CDIM + kw_) * LSTR + cio_;                \
    const bf16_t* pb3_ = (kw_ == 0) ? pB3_0 : ((kw_ == 1) ? pB3_1 : pB3_2);           \
    const bf16_t* b3_ = pb3_ + (size_t)(kh_ * CDIM) * LSTR + cio_;                    \
    bf16x8 m0_ = *(const bf16x8*)(b0_);                                               \
    bf16x8 m1_ = *(const bf16x8*)(b0_ + 16 * LSTR);                                   \
    bf16x8 m2_ = *(const bf16x8*)(b0_ + 32 * LSTR);                                   \
    bf16x8 m3_ = *(const bf16x8*)(b3_);                                               \
    __builtin_amdgcn_s_setprio(1);                                                    \
    acc[0][0] = __builtin_amdgcn_mfma_f32_16x16x32_bf16(F0v, m0_, acc[0][0], 0,0,0);  \
    acc[1][0] = __builtin_amdgcn_mfma_f32_16x16x32_bf16(F1v, m0_, acc[1][0], 0,0,0);  \
    acc[0][1] = __builtin_amdgcn_mfma_f32_16x16x32_bf16(F0v, m1_, acc[0][1], 0,0,0);  \
    acc[1][1] = __builtin_amdgcn_mfma_f32_16x16x32_bf16(F1v, m1_, acc[1][1], 0,0,0);  \
    acc[0][2] = __builtin_amdgcn_mfma_f32_16x16x32_bf16(F0v, m2_, acc[0][2], 0,0,0);  \
    acc[1][2] = __builtin_amdgcn_mfma_f32_16x16x32_bf16(F1v, m2_, acc[1][2], 0,0,0);  \
    acc[0][3] = __builtin_amdgcn_mfma_f32_16x16x32_bf16(F0v, m3_, acc[0][3], 0,0,0);  \
    acc[1][3] = __builtin_amdgcn_mfma_f32_16x16x32_bf16(F1v, m3_, acc[1][3], 0,0,0);  \
    __builtin_amdgcn_s_setprio(0);                                                    \
} while (0)

#define PREFETCH(I, F0v, F1v) do {                                                    \
    const bf16_t* wp_ = wpbase + FRAG_OFF(I);                                         \
    F0v = *(const bf16x8*)(wp_);                                                      \
    F1v = *(const bf16x8*)(wp_ + 512);                                                \
} while (0)

// stage one 512-thread sweep of units; HALF0: G in [0,1856) = ci 0..63 (record
// bytes 0..127), HALF1: G in [1856,3712) = ci 64..127 (record bytes 128..255)
#define STAGE_UNIT(G) do {                                                            \
    int G_ = (G);                                                                     \
    int cig = G_ / 232, rem = G_ - cig * 232;                                         \
    int rr  = rem / 58, c  = rem - rr * 58;                                           \
    int r_in = h0 - 1 + rr, w = c - 1;                                                \
    uint32_t u[8];                                                                    \
    if (r_in >= 0 && r_in < HH && w >= 0 && w < WW) {                                 \
        const float* src = in + (((size_t)n * CIN + cig * 8) * HH + r_in) * WW + w;   \
        float v[8];                                                                   \
        _Pragma("unroll")                                                             \
        for (int j = 0; j < 8; ++j) v[j] = src[(size_t)j * HW];                       \
        _Pragma("unroll")                                                             \
        for (int j = 0; j < 8; ++j) { bf16_t b = (bf16_t)v[j]; u[j] = *(const uint16_t*)&b; } \
    } else {                                                                          \
        _Pragma("unroll")                                                             \
        for (int j = 0; j < 8; ++j) u[j] = 0;                                         \
    }                                                                                 \
    uint4 o;                                                                          \
    o.x = u[0] | (u[1] << 16); o.y = u[2] | (u[3] << 16);                             \
    o.z = u[4] | (u[5] << 16); o.w = u[6] | (u[7] << 16);                             \
    *(uint4*)&inp[(rr * CDIM + c) * LSTR + cig * 8] = o;                              \
} while (0)

__global__ __launch_bounds__(512) __attribute__((amdgpu_waves_per_eu(4, 4)))
void conv_fused_kernel(const float* __restrict__ in, const bf16_t* __restrict__ Wt2,
                       const float* __restrict__ bias, float* __restrict__ out) {
    __shared__ __align__(16) unsigned char smem[63104];   // input stage only (no reduce buf)
    bf16_t* inp = (bf16_t*)smem;

    // XCD-aware swizzle: grid 448 = 8 XCDs x 56 blocks -> each XCD gets 2 whole
    // images (halo row re-reads become L2 hits).
    const int bx0 = blockIdx.x;
    const int bx  = (bx0 & 7) * 56 + (bx0 >> 3);

    const int n  = bx / ROWPAIRS;
    const int h0 = (bx % ROWPAIRS) * 2;          // output rows h0,h0+1; input rows h0-1..h0+2

    const int tid  = threadIdx.x;
    const int lane = tid & 63;
    const int wave = tid >> 6;                   // 0..7
    const int ws  = wave & 1;                    // output row within pair
    const int wc  = wave >> 1;                   // cout quarter (32 co)
    const int l15 = lane & 15;
    const int l4  = lane >> 4;

    // ---- stage HALF0 (ci 0..63): units 0..1855 = 3 full sweeps + 320 tail
#pragma unroll
    for (int it = 0; it < 3; ++it) STAGE_UNIT(it * 512 + tid);
    if (tid < 320) STAGE_UNIT(1536 + tid);
    __syncthreads();                             // half0 ready; MFMA on ci<64 can start

    // ---- stage HALF1 (ci 64..127): units 1856..3711; writes record bytes 128..255,
    // disjoint from everything phases 0..17 read -> overlaps with first K half.
#pragma unroll
    for (int it = 0; it < 3; ++it) STAGE_UNIT(1856 + it * 512 + tid);
    if (tid < 320) STAGE_UNIT(3392 + tid);

    f32x4 acc[2][4];                             // [tc][ts] -> 32 AGPRs
#pragma unroll
    for (int a = 0; a < 2; ++a)
#pragma unroll
        for (int b2 = 0; b2 < 4; ++b2) acc[a][b2] = (f32x4){0.f, 0.f, 0.f, 0.f};

    // bias preload (8 values this thread will need; L2-hot after first block)
    float bco[8];
#pragma unroll
    for (int tc = 0; tc < 2; ++tc)
#pragma unroll
        for (int i = 0; i < 4; ++i) bco[tc * 4 + i] = bias[wc * 32 + tc * 16 + l4 * 4 + i];

    // LDS B bases (ws, lane folded in; all phase offsets are compile-time imms)
    const bf16_t* pB = inp + (size_t)(ws * CDIM + l15) * LSTR + l4 * 8;
    int c3_0 = 48 + l15;     if (c3_0 > 57) c3_0 = 57;    // ts=3 clamped cols per kw
    int c3_1 = 48 + l15 + 1; if (c3_1 > 57) c3_1 = 57;
    int c3_2 = 48 + l15 + 2; if (c3_2 > 57) c3_2 = 57;
    const bf16_t* pB3_0 = inp + (size_t)(ws * CDIM + c3_0) * LSTR + l4 * 8;
    const bf16_t* pB3_1 = inp + (size_t)(ws * CDIM + c3_1) * LSTR + l4 * 8;
    const bf16_t* pB3_2 = inp + (size_t)(ws * CDIM + c3_2) * LSTR + l4 * 8;

    // weight fragment base: rec = (khkw*4 + chunk)*8 + wc*2 + tc
    const bf16_t* wpbase = Wt2 + (size_t)(wc * 2) * 512 + (size_t)lane * 8;

    bf16x8 A0, A1, B0, B1;                       // 2 frags/phase, prefetch distance 2
    PREFETCH(0, A0, A1);
    PREFETCH(1, B0, B1);

    // ---- K half 0: phases 0..17 (ci < 64)
#pragma unroll
    for (int ii = 0; ii < 8; ++ii) {
        const int i0 = ii * 2;
        DO_PHASE(i0, A0, A1);
        PREFETCH(i0 + 2, A0, A1);
        DO_PHASE(i0 + 1, B0, B1);
        PREFETCH(i0 + 3, B0, B1);
    }
    DO_PHASE(16, A0, A1);
    PREFETCH(18, A0, A1);
    DO_PHASE(17, B0, B1);
    PREFETCH(19, B0, B1);

    __syncthreads();                             // half1 LDS writes complete

    // ---- K half 1: phases 18..35 (ci >= 64)
#pragma unroll
    for (int ii = 9; ii < 17; ++ii) {
        const int i0 = ii * 2;
        DO_PHASE(i0, A0, A1);
        PREFETCH(i0 + 2, A0, A1);
        DO_PHASE(i0 + 1, B0, B1);
        PREFETCH(i0 + 3, B0, B1);
    }
    DO_PHASE(34, A0, A1);
    DO_PHASE(35, B0, B1);

    // ---- epilogue: direct store, every wave owns its outputs (no K reduction)
    {
        const int h = h0 + ws;
        float* obase = out + ((size_t)n * COUT) * HW + (size_t)h * WW;
#pragma unroll
        for (int tc = 0; tc < 2; ++tc) {
#pragma unroll
            for (int ts = 0; ts < 4; ++ts) {
                f32x4 r = acc[tc][ts];
                int w0 = ts * 16 + l15;
                if (w0 < WW) {
#pragma unroll
                    for (int i = 0; i < 4; ++i) {
                        int co = wc * 32 + tc * 16 + l4 * 4 + i;
                        obase[(size_t)co * HW + w0] = r[i] + bco[tc * 4 + i];
                    }
                }
            }
        }
    }
}

extern "C" void kernel_launch(void* const* d_in, const int* in_sizes, int n_in,
                              void* d_out, int out_size, void* d_ws, size_t ws_size,
                              hipStream_t stream) {
    const float* in   = (const float*)d_in[0];
    const float* wgt  = (const float*)d_in[1];
    const float* bias = (const float*)d_in[2];
    float* out = (float*)d_out;

    bf16_t* Wt2 = (bf16_t*)d_ws;                 // 294,912 B, fragment-major

    wtrans_kernel<<<72, 256, 0, stream>>>(wgt, Wt2);
    conv_fused_kernel<<<NIMG * ROWPAIRS, 512, 0, stream>>>(in, Wt2, bias, out);
}